// Round 1
// baseline (1682.481 us; speedup 1.0000x reference)
//
#include <hip/hip_runtime.h>
#include <cstdint>
#include <cstddef>
#include <cmath>

// ---------------------------------------------------------------------------
// Round 6: replace reg-staged GEMM staging with global_load_lds (dwordx4)
// + both-sides XOR swizzle (rule #21 / m173): LDS stays linear [128][32]u16,
// the 16B slot index is XORed with (row&3) on the global SOURCE address and
// on the ds_read fragment address. K-strides of all split operands padded to
// 32 with exact zeros so no lane predication is needed on the K edge.
// Keeps: split-bf16 (hi/lo) 3-MFMA core, 128x128x32 tiles, XCD-ownership
// tile swizzle. MP kernel flattened over (node,chunk) for lane efficiency.
// ---------------------------------------------------------------------------

#define EPS_BN 1e-5f

typedef unsigned short u16;
typedef short short8 __attribute__((ext_vector_type(8)));
typedef u16 u16x8 __attribute__((ext_vector_type(8)));
typedef u16 u16x4 __attribute__((ext_vector_type(4)));
typedef float fx4 __attribute__((ext_vector_type(4)));

__device__ __forceinline__ u16 bf16_rn(float f) {
  unsigned u = __float_as_uint(f);
  return (u16)((u + 0x7FFFu + ((u >> 16) & 1u)) >> 16);
}
__device__ __forceinline__ float bf16_f(u16 h) {
  return __uint_as_float(((unsigned)h) << 16);
}

// async global->LDS, 16B per lane; LDS dest = wave-uniform base + lane*16
__device__ __forceinline__ void gload16(const void* g, void* l) {
  __builtin_amdgcn_global_load_lds(
      (const __attribute__((address_space(1))) void*)g,
      (__attribute__((address_space(3))) void*)l, 16, 0, 0);
}

// ---- XCD-ownership swizzle: bijection blockIdx -> (mt, nt) ----------------
__device__ __forceinline__ void map_tile(int b, int tm, int tn, int T,
                                         int& mt, int& nt) {
  const int x = b & 7;
  const int s = b >> 3;
  const int cap = ((tm - x + 7) >> 3) * tn;  // slots in x's owned region
  if (s < cap) {
    const int q = s / tn;
    mt = x + (q << 3);
    nt = s - q * tn;
    return;
  }
  int r = s - cap;  // overflow rank (within this XCD's overflow)
  for (int xp = 0; xp < x; ++xp) {
    const int nbp = (T - xp + 7) >> 3;
    const int capp = ((tm - xp + 7) >> 3) * tn;
    if (nbp > capp) r += nbp - capp;
  }
  for (int xq = 0; xq < 8; ++xq) {
    const int nbq = (T - xq + 7) >> 3;
    const int capq = ((tm - xq + 7) >> 3) * tn;
    const int def = capq - nbq;
    if (def > 0) {
      if (r < def) {
        const int sq = nbq + r;
        const int q = sq / tn;
        mt = xq + (q << 3);
        nt = sq - q * tn;
        return;
      }
      r -= def;
    }
  }
  mt = 0; nt = 0;  // unreachable
}

// ============================ MFMA GEMM ====================================
// C(MxN) = act(A @ B + bias). A: M x K split bf16 (lda-strided, K-pads = 0),
// or fp32 if SPLITA (K%32==0 required on that path). B pre-transposed+split:
// Bhi/Blo are N x K bf16 (ldb-strided, K-pads = 0). OUTMODE 0: fp32 C
// (zero-fills cols [N,ldc)). OUTMODE 1: bias+relu -> split bf16 (zero pads).
// Block 128x128, BK=32, 4 waves (2x2), wave 64x64 as 4x4 MFMA 16x16x32;
// 3 MFMAs per (a,b) pair (hihi, hilo, lohi).
template <int OUTMODE, bool SPLITA>
__global__ __launch_bounds__(256, 2) void gemm_mfma(
    const u16* __restrict__ Ahi, const u16* __restrict__ Alo,
    const float* __restrict__ Af,
    const u16* __restrict__ Bhi, const u16* __restrict__ Blo,
    const float* __restrict__ bias,
    float* __restrict__ Cf, u16* __restrict__ Chi, u16* __restrict__ Clo,
    int M, int N, int K, int lda, int ldb, int ldc, int tm, int tn) {
  __shared__ __align__(16) u16 As[2][128 * 32];
  __shared__ __align__(16) u16 Bs[2][128 * 32];

  int mt, nt;
  map_tile(blockIdx.x, tm, tn, tm * tn, mt, nt);
  const int m0 = mt * 128;
  const int n0 = nt * 128;

  const int tid = threadIdx.x;
  const int lane = tid & 63;
  const int wid = tid >> 6;
  const int wm = (wid >> 1) * 64;
  const int wn = (wid & 1) * 64;
  const int quad = lane >> 4;
  const int l15 = lane & 15;

  // ---- staging geometry: thread -> (row = tid>>2, 16B slot = tid&3) ----
  const int srow = tid >> 2;                    // 0..63 (inst0); +64 (inst1)
  const int sg = ((tid & 3) ^ srow) & 3;        // swizzled global k-slot
  int ar0 = m0 + srow;      if (ar0 >= M) ar0 = M - 1;   // clamp: finite data,
  int ar1 = m0 + srow + 64; if (ar1 >= M) ar1 = M - 1;   // results discarded
  int br0 = n0 + srow;      if (br0 >= N) br0 = N - 1;
  int br1 = n0 + srow + 64; if (br1 >= N) br1 = N - 1;
  const size_t aof0 = (size_t)ar0 * lda + (sg << 3);
  const size_t aof1 = (size_t)ar1 * lda + (sg << 3);
  const size_t bof0 = (size_t)br0 * ldb + (sg << 3);
  const size_t bof1 = (size_t)br1 * ldb + (sg << 3);
  const int l0 = wid << 9;           // wave-uniform LDS base, u16 units
  const int l1 = 2048 + (wid << 9);  // rows 64..127 region
  const int wls = srow * 32 + ((tid & 3) << 3);  // SPLITA ds_write pos (linear)

  fx4 zf = {0.f, 0.f, 0.f, 0.f};
  fx4 acc[4][4];
#pragma unroll
  for (int a = 0; a < 4; ++a)
#pragma unroll
    for (int b = 0; b < 4; ++b) acc[a][b] = zf;

  const int nk = (K + 31) >> 5;
  for (int ki = 0; ki < nk; ++ki) {
    const int k0 = ki << 5;
    u16x8 va_h[2], va_l[2];
    if (SPLITA) {
      // fp32 A load + on-the-fly split (issued before barrier; K%32==0 here)
#pragma unroll
      for (int it = 0; it < 2; ++it) {
        const float* pp = Af + (it ? aof1 : aof0) + k0;
        const fx4 f0 = *(const fx4*)pp;
        const fx4 f1 = *(const fx4*)(pp + 4);
        u16x8 h, l;
#pragma unroll
        for (int j = 0; j < 4; ++j) {
          const u16 hb = bf16_rn(f0[j]);
          h[j] = hb;
          l[j] = bf16_rn(f0[j] - bf16_f(hb));
        }
#pragma unroll
        for (int j = 0; j < 4; ++j) {
          const u16 hb = bf16_rn(f1[j]);
          h[4 + j] = hb;
          l[4 + j] = bf16_rn(f1[j] - bf16_f(hb));
        }
        va_h[it] = h;
        va_l[it] = l;
      }
    }

    if (ki) __syncthreads();  // previous tile's frag reads done

    if (SPLITA) {
      gload16(Bhi + bof0 + k0, &Bs[0][l0]);
      gload16(Bhi + bof1 + k0, &Bs[0][l1]);
      gload16(Blo + bof0 + k0, &Bs[1][l0]);
      gload16(Blo + bof1 + k0, &Bs[1][l1]);
      *(u16x8*)&As[0][wls] = va_h[0];
      *(u16x8*)&As[0][wls + 2048] = va_h[1];
      *(u16x8*)&As[1][wls] = va_l[0];
      *(u16x8*)&As[1][wls + 2048] = va_l[1];
    } else {
      gload16(Ahi + aof0 + k0, &As[0][l0]);
      gload16(Ahi + aof1 + k0, &As[0][l1]);
      gload16(Alo + aof0 + k0, &As[1][l0]);
      gload16(Alo + aof1 + k0, &As[1][l1]);
      gload16(Bhi + bof0 + k0, &Bs[0][l0]);
      gload16(Bhi + bof1 + k0, &Bs[0][l1]);
      gload16(Blo + bof0 + k0, &Bs[1][l0]);
      gload16(Blo + bof1 + k0, &Bs[1][l1]);
    }
    __syncthreads();  // drains vmcnt (gload_lds) + lgkm (ds_write)

    short8 ah[4], al[4], bh[4], bl[4];
#pragma unroll
    for (int t = 0; t < 4; ++t) {
      const int rA = wm + t * 16 + l15;
      const int oa = rA * 32 + (((quad ^ rA) & 3) << 3);  // read-side swizzle
      ah[t] = *(const short8*)&As[0][oa];
      al[t] = *(const short8*)&As[1][oa];
      const int rB = wn + t * 16 + l15;
      const int ob = rB * 32 + (((quad ^ rB) & 3) << 3);
      bh[t] = *(const short8*)&Bs[0][ob];
      bl[t] = *(const short8*)&Bs[1][ob];
    }
#pragma unroll
    for (int a = 0; a < 4; ++a)
#pragma unroll
      for (int b = 0; b < 4; ++b) {
        acc[a][b] = __builtin_amdgcn_mfma_f32_16x16x32_bf16(ah[a], bh[b], acc[a][b], 0, 0, 0);
        acc[a][b] = __builtin_amdgcn_mfma_f32_16x16x32_bf16(ah[a], bl[b], acc[a][b], 0, 0, 0);
        acc[a][b] = __builtin_amdgcn_mfma_f32_16x16x32_bf16(al[a], bh[b], acc[a][b], 0, 0, 0);
      }
  }

#pragma unroll
  for (int a = 0; a < 4; ++a)
#pragma unroll
    for (int b = 0; b < 4; ++b) {
      const int gn = n0 + wn + b * 16 + l15;
      if (gn >= ldc) continue;
      const bool live = gn < N;
      const float bv = (OUTMODE == 1 && live) ? bias[gn] : 0.f;
#pragma unroll
      for (int r = 0; r < 4; ++r) {
        const int gm = m0 + wm + a * 16 + quad * 4 + r;
        if (gm >= M) continue;
        float v = live ? acc[a][b][r] : 0.f;  // zero K-pad cols for consumers
        if (OUTMODE == 1) {
          v = live ? fmaxf(v + bv, 0.f) : 0.f;
          const u16 hb = bf16_rn(v);
          Chi[(size_t)gm * ldc + gn] = hb;
          Clo[(size_t)gm * ldc + gn] = bf16_rn(v - bf16_f(hb));
        } else {
          Cf[(size_t)gm * ldc + gn] = v;
        }
      }
    }
}

// ================= weight prep: transpose + split (batched) ================
// Writes N x Kp (Kp = K rounded to 32) with exact zeros in K-pads.
struct TSJob { const float* W; u16* Th; u16* Tl; int K; int Kp; int N; int tiles_k; int base; };
struct TSJobs { TSJob j[12]; };

__global__ __launch_bounds__(256) void transpose_split_all(TSJobs jobs, int njobs) {
  const int b = blockIdx.x;
  int ji = 0;
  while (ji + 1 < njobs && jobs.j[ji + 1].base <= b) ++ji;
  const TSJob J = jobs.j[ji];
  const int t = b - J.base;
  const int k0 = (t % J.tiles_k) * 32;
  const int n0 = (t / J.tiles_k) * 32;
  __shared__ float tile[32][33];
  const int tx = threadIdx.x & 31, ty = threadIdx.x >> 5;
#pragma unroll
  for (int i = 0; i < 32; i += 8) {
    const int k = k0 + ty + i, n = n0 + tx;
    tile[ty + i][tx] = (k < J.K && n < J.N) ? J.W[(size_t)k * J.N + n] : 0.f;
  }
  __syncthreads();
#pragma unroll
  for (int i = 0; i < 32; i += 8) {
    const int n = n0 + ty + i, k = k0 + tx;
    if (n < J.N && k < J.Kp) {
      const float f = tile[tx][ty + i];  // 0 for k >= K -> zero K-pads
      const u16 hb = bf16_rn(f);
      J.Th[(size_t)n * J.Kp + k] = hb;
      J.Tl[(size_t)n * J.Kp + k] = bf16_rn(f - bf16_f(hb));
    }
  }
}

// ========================= Graph preprocessing =============================
__global__ void count_deg(const int* __restrict__ dst, int E, int* __restrict__ cnt) {
  int e = blockIdx.x * blockDim.x + threadIdx.x;
  if (e < E) atomicAdd(&cnt[dst[e]], 1);
}

__global__ void compute_dinv(const int* __restrict__ cnt, float* __restrict__ dinv, int N) {
  int i = blockIdx.x * blockDim.x + threadIdx.x;
  if (i < N) dinv[i] = rsqrtf((float)(cnt[i] + 1));  // +1 self-loop
}

__global__ void scan_block(const int* __restrict__ cnt, int* __restrict__ partial,
                           int* __restrict__ blocksum, int N) {
  __shared__ int s[256];
  const int t = threadIdx.x;
  const int i = blockIdx.x * 256 + t;
  int v = (i < N) ? cnt[i] : 0;
  s[t] = v;
  __syncthreads();
  for (int off = 1; off < 256; off <<= 1) {
    int u = (t >= off) ? s[t - off] : 0;
    __syncthreads();
    s[t] += u;
    __syncthreads();
  }
  if (i < N) partial[i] = s[t];
  if (t == 255) blocksum[blockIdx.x] = s[255];
}

__global__ void scan_sums(int* __restrict__ blocksum, int NB) {
  __shared__ int s[256];
  const int t = threadIdx.x;
  int v = (t < NB) ? blocksum[t] : 0;
  s[t] = v;
  __syncthreads();
  for (int off = 1; off < 256; off <<= 1) {
    int u = (t >= off) ? s[t - off] : 0;
    __syncthreads();
    s[t] += u;
    __syncthreads();
  }
  if (t < NB) blocksum[t] = s[t] - v;  // exclusive
}

__global__ void finalize_rowptr(const int* __restrict__ partial, const int* __restrict__ blockoff,
                                int* __restrict__ rowptr, int N) {
  int i = blockIdx.x * 256 + threadIdx.x;
  if (i < N) rowptr[i + 1] = partial[i] + blockoff[blockIdx.x];
  if (i == 0) rowptr[0] = 0;
}

__global__ void fill_csr(const int* __restrict__ src, const int* __restrict__ dst, int E,
                         const int* __restrict__ rowptr, int* __restrict__ cursor,
                         int* __restrict__ colidx) {
  int e = blockIdx.x * blockDim.x + threadIdx.x;
  if (e < E) {
    int d = dst[e];
    int p = atomicAdd(&cursor[d], 1);
    colidx[rowptr[d] + p] = src[e];
  }
}

// ================= Message passing + bias + BN + ReLU ======================
// Flattened over (node, fx4-chunk) for ~full lane efficiency at small F.
// H stride = Fp; output stride = Fp with exact zeros in [F, Fp) (K-pads of
// the next layer's GEMM A-operand).
__global__ void mp_bn_relu(
    const float* __restrict__ H, const int* __restrict__ rowptr,
    const int* __restrict__ colidx, const float* __restrict__ dinv,
    const float* __restrict__ gb, const float* __restrict__ gamma,
    const float* __restrict__ beta, const float* __restrict__ mean,
    const float* __restrict__ var,
    u16* __restrict__ Xh, u16* __restrict__ Xl, int N, int F, int Fp) {
  const int nch = Fp >> 2;
  const int idx = blockIdx.x * blockDim.x + threadIdx.x;
  if (idx >= N * nch) return;
  const int i = idx / nch;
  const int c = idx - i * nch;
  const size_t rowi = (size_t)i * Fp + (c << 2);
  if ((c << 2) >= F) {
    const u16x4 z = {0, 0, 0, 0};
    *(u16x4*)(Xh + rowi) = z;
    *(u16x4*)(Xl + rowi) = z;
    return;
  }
  const float di = dinv[i];
  fx4 acc = (di * di) * *(const fx4*)(H + rowi);
  const int e0 = rowptr[i], e1 = rowptr[i + 1];
  int e = e0;
  for (; e + 4 <= e1; e += 4) {
    const int s0 = colidx[e + 0], s1 = colidx[e + 1];
    const int s2 = colidx[e + 2], s3 = colidx[e + 3];
    const float w0 = di * dinv[s0], w1 = di * dinv[s1];
    const float w2 = di * dinv[s2], w3 = di * dinv[s3];
    const fx4 v0 = *(const fx4*)(H + (size_t)s0 * Fp + (c << 2));
    const fx4 v1 = *(const fx4*)(H + (size_t)s1 * Fp + (c << 2));
    const fx4 v2 = *(const fx4*)(H + (size_t)s2 * Fp + (c << 2));
    const fx4 v3 = *(const fx4*)(H + (size_t)s3 * Fp + (c << 2));
    acc += w0 * v0;
    acc += w1 * v1;
    acc += w2 * v2;
    acc += w3 * v3;
  }
  for (; e < e1; ++e) {
    const int s = colidx[e];
    acc += (di * dinv[s]) * *(const fx4*)(H + (size_t)s * Fp + (c << 2));
  }
  u16x4 oh, ol;
#pragma unroll
  for (int j = 0; j < 4; ++j) {
    const int col = (c << 2) + j;
    float v = (acc[j] + gb[col] - mean[col]) * rsqrtf(var[col] + EPS_BN) * gamma[col] + beta[col];
    v = fmaxf(v, 0.f);
    const u16 hb = bf16_rn(v);
    oh[j] = hb;
    ol[j] = bf16_rn(v - bf16_f(hb));
  }
  *(u16x4*)(Xh + rowi) = oh;
  *(u16x4*)(Xl + rowi) = ol;
}

// ========================= global max pool (segments) ======================
__global__ void pool_seg(const u16* __restrict__ Xh, const u16* __restrict__ Xl,
                         const int* __restrict__ batch, float* __restrict__ out,
                         int N, int F, int ldx) {
  const int g = blockIdx.x;
  int lo = 0, hi = N;
  while (lo < hi) { int m = (lo + hi) >> 1; if (batch[m] < g) lo = m + 1; else hi = m; }
  const int s0 = lo;
  hi = N;
  while (lo < hi) { int m = (lo + hi) >> 1; if (batch[m] <= g) lo = m + 1; else hi = m; }
  const int s1 = lo;
  const int c = threadIdx.x;
  if (c * 4 >= F) return;
  fx4 mx = {-INFINITY, -INFINITY, -INFINITY, -INFINITY};
  for (int i = s0; i < s1; ++i) {
    const size_t off = (size_t)i * ldx + (c << 2);
    const u16x4 h = *(const u16x4*)(Xh + off);
    const u16x4 l = *(const u16x4*)(Xl + off);
#pragma unroll
    for (int j = 0; j < 4; ++j) mx[j] = fmaxf(mx[j], bf16_f(h[j]) + bf16_f(l[j]));
  }
  *(fx4*)(out + (size_t)g * F + (c << 2)) = mx;
}

// =========================== launch ========================================
extern "C" void kernel_launch(void* const* d_in, const int* in_sizes, int n_in,
                              void* d_out, int out_size, void* d_ws, size_t ws_size,
                              hipStream_t stream) {
  const float* x = (const float*)d_in[0];
  const int* edges = (const int*)d_in[1];
  const int* batch = (const int*)d_in[2];
  const int E = in_sizes[1] / 2;
  const int Nn = in_sizes[2];

  static const int FDS[4]  = {80, 160, 400, 600};
  static const int FDP[4]  = {96, 160, 416, 608};   // round32(fd)
  static const int DINS[4] = {3072, 80, 160, 400};
  static const int DINP[4] = {3072, 96, 160, 416};  // round32(din) == FDP[i-1]
  const float *wa[4], *ba[4], *wb[4], *bb[4], *gw[4], *gb[4], *gamma[4], *beta[4], *mean[4], *var[4];
  for (int i = 0; i < 4; ++i) {
    const int b = 3 + 10 * i;
    wa[i] = (const float*)d_in[b + 0];
    ba[i] = (const float*)d_in[b + 1];
    wb[i] = (const float*)d_in[b + 2];
    bb[i] = (const float*)d_in[b + 3];
    gw[i] = (const float*)d_in[b + 4];
    gb[i] = (const float*)d_in[b + 5];
    gamma[i] = (const float*)d_in[b + 6];
    beta[i] = (const float*)d_in[b + 7];
    mean[i] = (const float*)d_in[b + 8];
    var[i] = (const float*)d_in[b + 9];
  }

  // ---- workspace carve ----
  char* p = (char*)d_ws;
  auto alloc = [&](size_t bytes) {
    char* r = p;
    p += (bytes + 255) & ~(size_t)255;
    return r;
  };
  u16* actA_h = (u16*)alloc((size_t)Nn * 2400 * 2);  // H1 hi; H3(fp32) aliases head
  u16* actA_l = (u16*)alloc((size_t)Nn * 2400 * 2);  // H1 lo
  u16* actB_h = (u16*)alloc((size_t)Nn * 608 * 2);   // X / H2 hi (Fp-strided)
  u16* actB_l = (u16*)alloc((size_t)Nn * 608 * 2);   // X / H2 lo
  float* H3 = (float*)actA_h;  // Nn*608*4B <= Nn*2400*2B

  u16 *waT_h[4], *waT_l[4], *wbT_h[4], *wbT_l[4], *gwT_h[4], *gwT_l[4];
  for (int i = 0; i < 4; ++i) {
    const size_t s1 = (size_t)4 * FDS[i] * DINP[i];   // rows 4fd x ld dinp
    const size_t s2 = (size_t)FDS[i] * 4 * FDS[i];    // rows fd  x ld 4fd
    const size_t s3 = (size_t)FDS[i] * FDP[i];        // rows fd  x ld fdp
    waT_h[i] = (u16*)alloc(s1 * 2);
    waT_l[i] = (u16*)alloc(s1 * 2);
    wbT_h[i] = (u16*)alloc(s2 * 2);
    wbT_l[i] = (u16*)alloc(s2 * 2);
    gwT_h[i] = (u16*)alloc(s3 * 2);
    gwT_l[i] = (u16*)alloc(s3 * 2);
  }

  int* cnt = (int*)alloc((size_t)Nn * sizeof(int));
  int* cursor = (int*)alloc((size_t)Nn * sizeof(int));
  int* partial = (int*)alloc((size_t)Nn * sizeof(int));
  int* blocksum = (int*)alloc(256 * sizeof(int));
  int* rowptr = (int*)alloc((size_t)(Nn + 1) * sizeof(int));
  int* colidx = (int*)alloc((size_t)E * sizeof(int));
  float* dinv = (float*)alloc((size_t)Nn * sizeof(float));

  const int* srcIdx = edges;
  const int* dstIdx = edges + E;

  // ---- weight prep: one batched launch for all 12 transpose+splits ----
  {
    TSJobs jobs;
    int base = 0, ji = 0;
    auto addjob = [&](const float* W, int K, int Kp, int Ncols, u16* Th, u16* Tl) {
      const int tk = Kp / 32, tn = (Ncols + 31) / 32;
      jobs.j[ji++] = TSJob{W, Th, Tl, K, Kp, Ncols, tk, base};
      base += tk * tn;
    };
    for (int i = 0; i < 4; ++i) {
      addjob(wa[i], DINS[i], DINP[i], 4 * FDS[i], waT_h[i], waT_l[i]);
      addjob(wb[i], 4 * FDS[i], 4 * FDS[i], FDS[i], wbT_h[i], wbT_l[i]);
      addjob(gw[i], FDS[i], FDP[i], FDS[i], gwT_h[i], gwT_l[i]);
    }
    transpose_split_all<<<base, 256, 0, stream>>>(jobs, 12);
  }

  // ---- CSR build ----
  hipMemsetAsync(cnt, 0, (size_t)Nn * sizeof(int), stream);
  hipMemsetAsync(cursor, 0, (size_t)Nn * sizeof(int), stream);

  const int EB = (E + 255) / 256;
  const int NB = (Nn + 255) / 256;
  count_deg<<<EB, 256, 0, stream>>>(dstIdx, E, cnt);
  compute_dinv<<<NB, 256, 0, stream>>>(cnt, dinv, Nn);
  scan_block<<<NB, 256, 0, stream>>>(cnt, partial, blocksum, Nn);
  scan_sums<<<1, 256, 0, stream>>>(blocksum, NB);
  finalize_rowptr<<<NB, 256, 0, stream>>>(partial, blocksum, rowptr, Nn);
  fill_csr<<<EB, 256, 0, stream>>>(srcIdx, dstIdx, E, rowptr, cursor, colidx);

  // ---- layers ----
  const int tm = (Nn + 127) / 128;
  for (int i = 0; i < 4; ++i) {
    const int fd = FDS[i], fdp = FDP[i];
    const int hid = 4 * fd;          // always a multiple of 32
    const int din = DINS[i], dinp = DINP[i];

    // G1: X @ wa + ba, relu -> H1 (split, ldc = hid)
    {
      const int tn = (hid + 127) / 128;
      if (i == 0) {
        gemm_mfma<1, true><<<tm * tn, 256, 0, stream>>>(
            nullptr, nullptr, x, waT_h[0], waT_l[0], ba[0],
            nullptr, actA_h, actA_l, Nn, hid, din, din, dinp, hid, tm, tn);
      } else {
        gemm_mfma<1, false><<<tm * tn, 256, 0, stream>>>(
            actB_h, actB_l, nullptr, waT_h[i], waT_l[i], ba[i],
            nullptr, actA_h, actA_l, Nn, hid, din, dinp, dinp, hid, tm, tn);
      }
    }
    // G2: H1 @ wb + bb, relu -> H2 (split, ldc = fdp, zero pads)
    {
      const int tn = (fd + 127) / 128;
      gemm_mfma<1, false><<<tm * tn, 256, 0, stream>>>(
          actA_h, actA_l, nullptr, wbT_h[i], wbT_l[i], bb[i],
          nullptr, actB_h, actB_l, Nn, fd, hid, hid, hid, fdp, tm, tn);
    }
    // G3: H2 @ gw -> H3 (fp32, ldc = fdp, zero pads; aliases H1 region)
    {
      const int tn = (fd + 127) / 128;
      gemm_mfma<0, false><<<tm * tn, 256, 0, stream>>>(
          actB_h, actB_l, nullptr, gwT_h[i], gwT_l[i], nullptr,
          H3, nullptr, nullptr, Nn, fd, fd, fdp, fdp, fdp, tm, tn);
    }
    // MP + bias + BN + ReLU -> X_next (split, Fp-strided, zero pads)
    {
      const int items = Nn * (fdp >> 2);
      mp_bn_relu<<<(items + 255) / 256, 256, 0, stream>>>(
          H3, rowptr, colidx, dinv, gb[i], gamma[i], beta[i], mean[i], var[i],
          actB_h, actB_l, Nn, fd, fdp);
    }
  }

  pool_seg<<<out_size / 600, 192, 0, stream>>>(actB_h, actB_l, batch, (float*)d_out,
                                               Nn, 600, 608);
}